// Round 1
// 3717.089 us; speedup vs baseline: 1.0972x; 1.0972x over previous
//
#include <hip/hip_runtime.h>

#define BB 4
#define TT 2048
#define HH 128
#define VV 32000

typedef __attribute__((ext_vector_type(8))) _Float16 half8;
typedef __attribute__((ext_vector_type(4))) float floatx4;

// ---------------------------------------------------------------------------
// K1: pre-activation GEMM for layer 0 only.
//   out[row][j] = dot(emb[x[row]], Wih0[j][:]) + b_ih0[j] + b_hh0[j]
// grid = B*T blocks, 128 threads (thread j computes one output).
// ---------------------------------------------------------------------------
__global__ void preact_kernel(const float* __restrict__ src,
                              const int* __restrict__ idx,
                              const float* __restrict__ Wih,
                              const float* __restrict__ b1,
                              const float* __restrict__ b2,
                              float* __restrict__ out) {
    __shared__ float xs[HH];
    int row = blockIdx.x;
    int j = threadIdx.x;
    const float* srow = idx ? (src + (long)idx[row] * HH) : (src + (long)row * HH);
    xs[j] = srow[j];
    __syncthreads();
    const float* wrow = Wih + j * HH;
    float a0 = 0.f, a1 = 0.f, a2 = 0.f, a3 = 0.f;
#pragma unroll
    for (int k = 0; k < HH; k += 4) {
        float4 w = *(const float4*)(wrow + k);
        a0 += w.x * xs[k + 0];
        a1 += w.y * xs[k + 1];
        a2 += w.z * xs[k + 2];
        a3 += w.w * xs[k + 3];
    }
    out[(long)row * HH + j] = (a0 + a1) + (a2 + a3) + b1[j] + b2[j];
}

// ---------------------------------------------------------------------------
// K2: FUSED 2-layer Elman recurrence, software-pipelined (layer1 lags by 1).
// grid = B blocks (4), 256 threads = 4 identical waves.
// Thread (w = tid>>6, l = tid&63): half = l>>5, j = w*32 + (l&31).
// Register-resident weights per thread:
//   w0r[64]  = Whh0[j][half*64 .. half*64+64)
//   w1r[128] = (half==0 ? Wih1 : Whh1)[j][0..128)
// Iteration i in [0, TT]:
//   layer0 (i<TT):  h0new = tanh(dot(Whh0[j], h0[i-1]) + pre0[i][j])
//   layer1 (i>=1):  h1new = tanh(dot(Wih1[j], h0[i-1]) + dot(Whh1[j], h1[i-2]) + b)
// Each dot split across the two halves of a wave; one __shfl_xor(.,32) reduce.
// h state double-buffered in LDS: read buf (i&1)^1, write buf i&1 ->
// exactly ONE __syncthreads per step.
// Per-step VALU floor: 192 MAC/thread = 384 cy/SIMD, balanced on all 4 waves.
// ---------------------------------------------------------------------------
__global__ void __launch_bounds__(256, 1) rnn_fused_kernel(
        const float* __restrict__ pre0,  // [B,T,H] = emb@Wih0^T + bih0 + bhh0
        const float* __restrict__ Whh0,  // [H,H]
        const float* __restrict__ Wih1,  // [H,H]
        const float* __restrict__ Whh1,  // [H,H]
        const float* __restrict__ bih1,  // [H]
        const float* __restrict__ bhh1,  // [H]
        const float* __restrict__ hin,   // [2,B,H] initial hidden
        float* __restrict__ out1,        // [B,T,H] layer-1 outputs (logits input)
        float* __restrict__ hout) {      // [2,B,H] final hidden
    __shared__ float hs0[2][HH];
    __shared__ float hs1[2][HH];
    const int b = blockIdx.x;
    const int tid = threadIdx.x;
    const int l = tid & 63;
    const int half = l >> 5;
    const int j = (tid >> 6) * 32 + (l & 31);

    // Weights into VGPRs (one-time).
    float w0r[64];
    {
        const float* s = Whh0 + j * HH + half * 64;
#pragma unroll
        for (int q = 0; q < 16; q++) {
            float4 v = *(const float4*)(s + q * 4);
            w0r[4 * q + 0] = v.x; w0r[4 * q + 1] = v.y;
            w0r[4 * q + 2] = v.z; w0r[4 * q + 3] = v.w;
        }
    }
    float w1r[128];
    {
        const float* s = (half ? Whh1 : Wih1) + j * HH;
#pragma unroll
        for (int q = 0; q < 32; q++) {
            float4 v = *(const float4*)(s + q * 4);
            w1r[4 * q + 0] = v.x; w1r[4 * q + 1] = v.y;
            w1r[4 * q + 2] = v.z; w1r[4 * q + 3] = v.w;
        }
    }
    const float bias1 = bih1[j] + bhh1[j];

    // Initial state: h0 init read at i=0 (rb=1), h1 init read at i=1 (rb=0).
    if (tid < HH) {
        hs0[1][tid] = hin[b * HH + tid];
        hs1[0][tid] = hin[(BB + b) * HH + tid];
    }
    __syncthreads();

    const float* prow = pre0 + ((long)b * TT) * HH + j;
    float pnext = prow[0];  // prefetch pre0 for i=0
    for (int i = 0; i <= TT; i++) {
        const int rb = (i & 1) ^ 1;
        const int wb = i & 1;
        float p = pnext;
        if (i + 1 < TT) pnext = prow[(long)(i + 1) * HH];  // prefetch next step

        // Layer 0 partial: 64 MACs over hs0[rb][half*64 .. +64).
        float a0 = 0.f, a1 = 0.f, a2 = 0.f, a3 = 0.f;
        if (i < TT) {
#pragma unroll
            for (int q = 0; q < 16; q++) {
                float4 h4 = *(const float4*)(&hs0[rb][half * 64 + q * 4]);
                a0 += h4.x * w0r[4 * q + 0];
                a1 += h4.y * w0r[4 * q + 1];
                a2 += h4.z * w0r[4 * q + 2];
                a3 += h4.w * w0r[4 * q + 3];
            }
        }
        // Layer 1 partial: 128 MACs; half0 = Wih1 . h0[i-1], half1 = Whh1 . h1[i-2].
        float c0 = 0.f, c1 = 0.f, c2 = 0.f, c3 = 0.f;
        if (i >= 1) {
            const float* hsrc = half ? &hs1[rb][0] : &hs0[rb][0];
#pragma unroll
            for (int q = 0; q < 32; q++) {
                float4 h4 = *(const float4*)(hsrc + q * 4);
                c0 += h4.x * w1r[4 * q + 0];
                c1 += h4.y * w1r[4 * q + 1];
                c2 += h4.z * w1r[4 * q + 2];
                c3 += h4.w * w1r[4 * q + 3];
            }
        }
        float acc0 = (a0 + a1) + (a2 + a3);
        float acc1 = (c0 + c1) + (c2 + c3);
        acc0 += __shfl_xor(acc0, 32);  // combine the two 64-halves of layer0 dot
        acc1 += __shfl_xor(acc1, 32);  // combine ih-part and hh-part of layer1 dot
        float hnew = tanhf(half ? (acc1 + bias1) : (acc0 + p));
        if (half == 0) {
            if (i < TT) hs0[wb][j] = hnew;
        } else {
            if (i >= 1) {
                hs1[wb][j] = hnew;
                out1[((long)b * TT + (i - 1)) * HH + j] = hnew;
            }
        }
        __syncthreads();  // write(i) -> read(i+1); also read(i) -> write(i+1)
    }
    // Final hidden: h0^{T-1} written at i=T-1 (buf (T-1)&1), h1^{T-1} at i=T (buf T&1).
    if (tid < HH) {
        hout[b * HH + tid] = hs0[(TT - 1) & 1][tid];
        hout[(BB + b) * HH + tid] = hs1[TT & 1][tid];
    }
}

// ---------------------------------------------------------------------------
// K3: logits = act @ fc_w^T + fc_b via f16 MFMA (16x16x32). (unchanged)
// Block tile 64(M) x 128(N), K=128 resident in LDS.
// ---------------------------------------------------------------------------
#define BM 64
#define BN 128
#define LDK 136

__global__ void __launch_bounds__(256) logits_kernel(
        const float* __restrict__ act,   // [8192,128]
        const float* __restrict__ fcw,   // [32000,128]
        const float* __restrict__ fcb,   // [32000]
        float* __restrict__ Cout) {      // [8192,32000]
    __shared__ __align__(16) _Float16 As[BM * LDK];
    __shared__ __align__(16) _Float16 Bs[BN * LDK];
    const int bn = blockIdx.x;
    const int bm = blockIdx.y;
    const int tid = threadIdx.x;

#pragma unroll
    for (int s = 0; s < 8; s++) {
        int f = tid + s * 256;
        int r = f >> 5, c4 = f & 31;
        float4 v = *(const float4*)(act + ((long)(bm * BM + r)) * HH + c4 * 4);
        _Float16* d = &As[r * LDK + c4 * 4];
        d[0] = (_Float16)v.x; d[1] = (_Float16)v.y;
        d[2] = (_Float16)v.z; d[3] = (_Float16)v.w;
    }
#pragma unroll
    for (int s = 0; s < 16; s++) {
        int f = tid + s * 256;
        int r = f >> 5, c4 = f & 31;
        float4 v = *(const float4*)(fcw + ((long)(bn * BN + r)) * HH + c4 * 4);
        _Float16* d = &Bs[r * LDK + c4 * 4];
        d[0] = (_Float16)v.x; d[1] = (_Float16)v.y;
        d[2] = (_Float16)v.z; d[3] = (_Float16)v.w;
    }
    __syncthreads();

    const int wv = tid >> 6;
    const int wm = wv >> 1, wn = wv & 1;
    const int r = tid & 15, q = (tid & 63) >> 4;

    floatx4 acc[2][4];
#pragma unroll
    for (int mt = 0; mt < 2; mt++)
#pragma unroll
        for (int nt = 0; nt < 4; nt++) acc[mt][nt] = (floatx4){0.f, 0.f, 0.f, 0.f};

#pragma unroll
    for (int kk = 0; kk < 4; kk++) {
        half8 af[2], bf[4];
#pragma unroll
        for (int mt = 0; mt < 2; mt++)
            af[mt] = *(const half8*)(&As[(wm * 32 + mt * 16 + r) * LDK + kk * 32 + q * 8]);
#pragma unroll
        for (int nt = 0; nt < 4; nt++)
            bf[nt] = *(const half8*)(&Bs[(wn * 64 + nt * 16 + r) * LDK + kk * 32 + q * 8]);
#pragma unroll
        for (int mt = 0; mt < 2; mt++)
#pragma unroll
            for (int nt = 0; nt < 4; nt++)
                acc[mt][nt] = __builtin_amdgcn_mfma_f32_16x16x32_f16(af[mt], bf[nt], acc[mt][nt], 0, 0, 0);
    }

#pragma unroll
    for (int mt = 0; mt < 2; mt++) {
#pragma unroll
        for (int nt = 0; nt < 4; nt++) {
            int gcol = bn * BN + wn * 64 + nt * 16 + r;
            float bias = fcb[gcol];
#pragma unroll
            for (int r4 = 0; r4 < 4; r4++) {
                int grow = bm * BM + wm * 32 + mt * 16 + q * 4 + r4;
                Cout[(long)grow * VV + gcol] = acc[mt][nt][r4] + bias;
            }
        }
    }
}

// ---------------------------------------------------------------------------
extern "C" void kernel_launch(void* const* d_in, const int* in_sizes, int n_in,
                              void* d_out, int out_size, void* d_ws, size_t ws_size,
                              hipStream_t stream) {
    const int*   x      = (const int*)d_in[0];
    const float* hidden = (const float*)d_in[1];
    const float* emb    = (const float*)d_in[2];
    const float* Wih0   = (const float*)d_in[3];
    const float* Whh0   = (const float*)d_in[4];
    const float* bih0   = (const float*)d_in[5];
    const float* bhh0   = (const float*)d_in[6];
    const float* Wih1   = (const float*)d_in[7];
    const float* Whh1   = (const float*)d_in[8];
    const float* bih1   = (const float*)d_in[9];
    const float* bhh1   = (const float*)d_in[10];
    const float* fcw    = (const float*)d_in[11];
    const float* fcb    = (const float*)d_in[12];

    float* logits = (float*)d_out;
    float* hout   = logits + (long)BB * TT * VV;   // new_hidden [2,B,H]

    float* wsA = (float*)d_ws;                     // [B,T,H] layer-0 pre-activations
    float* ws1 = wsA + (long)BB * TT * HH;         // [B,T,H] layer-1 outputs

    // Layer 0 pre-activations (embedding gather fused).
    preact_kernel<<<BB * TT, HH, 0, stream>>>(emb, x, Wih0, bih0, bhh0, wsA);
    // Fused 2-layer recurrence (layer-1 input matvec folded in; layer-0
    // outputs never touch global memory).
    rnn_fused_kernel<<<BB, 256, 0, stream>>>(wsA, Whh0, Wih1, Whh1, bih1, bhh1,
                                             hidden, ws1, hout);
    // Final projection to vocab.
    logits_kernel<<<dim3(VV / BN, (BB * TT) / BM), 256, 0, stream>>>(ws1, fcw, fcb, logits);
}

// Round 2
// 3056.190 us; speedup vs baseline: 1.3344x; 1.2162x over previous
//
#include <hip/hip_runtime.h>

#define BB 4
#define TT 2048
#define HH 128
#define VV 32000

typedef __attribute__((ext_vector_type(8))) _Float16 half8;
typedef __attribute__((ext_vector_type(4))) float floatx4;

// ---------------------------------------------------------------------------
// K1: pre-activation GEMM for layer 0 only.
//   out[row][j] = dot(emb[x[row]], Wih0[j][:]) + b_ih0[j] + b_hh0[j]
// grid = B*T blocks, 128 threads (thread j computes one output).
// ---------------------------------------------------------------------------
__global__ void preact_kernel(const float* __restrict__ src,
                              const int* __restrict__ idx,
                              const float* __restrict__ Wih,
                              const float* __restrict__ b1,
                              const float* __restrict__ b2,
                              float* __restrict__ out) {
    __shared__ float xs[HH];
    int row = blockIdx.x;
    int j = threadIdx.x;
    const float* srow = idx ? (src + (long)idx[row] * HH) : (src + (long)row * HH);
    xs[j] = srow[j];
    __syncthreads();
    const float* wrow = Wih + j * HH;
    float a0 = 0.f, a1 = 0.f, a2 = 0.f, a3 = 0.f;
#pragma unroll
    for (int k = 0; k < HH; k += 4) {
        float4 w = *(const float4*)(wrow + k);
        a0 += w.x * xs[k + 0];
        a1 += w.y * xs[k + 1];
        a2 += w.z * xs[k + 2];
        a3 += w.w * xs[k + 3];
    }
    out[(long)row * HH + j] = (a0 + a1) + (a2 + a3) + b1[j] + b2[j];
}

// ---------------------------------------------------------------------------
// K2: FUSED 2-layer Elman recurrence, software-pipelined (layer1 lags by 1).
// grid = B blocks (4), 512 threads = 8 waves, 2 per SIMD, balanced:
//   waves 0-3 (L1): lane (j = w*32 + (l&31), part = l>>5).
//     part0: dot(Wih1[j], h0[i-1])  part1: dot(Whh1[j], h1[i-2])  (128 MACs ea)
//   waves 4-7 (L0): j = (w-4)*32 + (l&31), part = l>>5.
//     dot(Whh0[j][part*64..+64), h0[i-1][part*64..+64))            (64 MACs ea)
// Cross-half combine via v_permlane32_swap (VALU, not ds_bpermute).
// Per SIMD per step: one L1 wave (128 FMA) + one L0 wave (64 FMA)
//   = 384 cy issue floor, stalls overlapped across the two waves.
// KEY: raw s_barrier + s_waitcnt lgkmcnt(0) ONLY — the per-step out1 global
// store and pre0 prefetch load stay in flight across the barrier (no
// vmcnt(0) drain on the 2049-step serial path, unlike __syncthreads()).
// h state double-buffered in LDS -> exactly ONE barrier per step.
// ---------------------------------------------------------------------------
__global__ void __launch_bounds__(512, 1) rnn_fused_kernel(
        const float* __restrict__ pre0,  // [B,T,H] = emb@Wih0^T + bih0 + bhh0
        const float* __restrict__ Whh0,  // [H,H]
        const float* __restrict__ Wih1,  // [H,H]
        const float* __restrict__ Whh1,  // [H,H]
        const float* __restrict__ bih1,  // [H]
        const float* __restrict__ bhh1,  // [H]
        const float* __restrict__ hin,   // [2,B,H] initial hidden
        float* __restrict__ out1,        // [B,T,H] layer-1 outputs (logits input)
        float* __restrict__ hout) {      // [2,B,H] final hidden
    __shared__ float hs0[2][HH];
    __shared__ float hs1[2][HH];
    const int b = blockIdx.x;
    const int tid = threadIdx.x;
    const int w = tid >> 6;
    const int l = tid & 63;
    const int part = l >> 5;
    const bool isL1 = (w < 4);
    const int j = (isL1 ? w : (w - 4)) * 32 + (l & 31);

    // Weights into VGPRs (one-time). L1 lanes hold a full 128-wide row
    // (Wih1 or Whh1 by half); L0 lanes hold a 64-wide half of Whh0[j].
    float wreg[128];
    if (isL1) {
        const float* s = (part ? Whh1 : Wih1) + j * HH;
#pragma unroll
        for (int q = 0; q < 32; q++) {
            float4 v = *(const float4*)(s + 4 * q);
            wreg[4 * q + 0] = v.x; wreg[4 * q + 1] = v.y;
            wreg[4 * q + 2] = v.z; wreg[4 * q + 3] = v.w;
        }
    } else {
        const float* s = Whh0 + j * HH + part * 64;
#pragma unroll
        for (int q = 0; q < 16; q++) {
            float4 v = *(const float4*)(s + 4 * q);
            wreg[4 * q + 0] = v.x; wreg[4 * q + 1] = v.y;
            wreg[4 * q + 2] = v.z; wreg[4 * q + 3] = v.w;
        }
    }
    const float bias1 = isL1 ? (bih1[j] + bhh1[j]) : 0.f;

    // Initial state: h0 init read at i=0 (rb=1), h1 init read at i=1 (rb=0).
    if (tid < HH) {
        hs0[1][tid] = hin[b * HH + tid];
        hs1[0][tid] = hin[(BB + b) * HH + tid];
    }
    __syncthreads();  // one-time; full fence is fine here

    const float* prow = pre0 + (long)b * TT * HH + j;
    float pnext = isL1 ? 0.f : prow[0];  // L0 prefetch for i=0

    for (int i = 0; i <= TT; i++) {
        const int rb = (i & 1) ^ 1;
        const int wb = i & 1;
        float p = pnext;
        if (!isL1 && (i + 1 < TT)) pnext = prow[(long)(i + 1) * HH];
        const bool active = isL1 ? (i >= 1) : (i < TT);

        float a0 = 0.f, a1 = 0.f, a2 = 0.f, a3 = 0.f;
        if (active) {
            if (isL1) {
                const float* hsrc = part ? &hs1[rb][0] : &hs0[rb][0];
#pragma unroll
                for (int q = 0; q < 32; q++) {
                    float4 h4 = *(const float4*)(hsrc + 4 * q);
                    a0 += h4.x * wreg[4 * q + 0];
                    a1 += h4.y * wreg[4 * q + 1];
                    a2 += h4.z * wreg[4 * q + 2];
                    a3 += h4.w * wreg[4 * q + 3];
                }
            } else {
                const float* hsrc = &hs0[rb][part * 64];
#pragma unroll
                for (int q = 0; q < 16; q++) {
                    float4 h4 = *(const float4*)(hsrc + 4 * q);
                    a0 += h4.x * wreg[4 * q + 0];
                    a1 += h4.y * wreg[4 * q + 1];
                    a2 += h4.z * wreg[4 * q + 2];
                    a3 += h4.w * wreg[4 * q + 3];
                }
            }
        }
        float acc = (a0 + a1) + (a2 + a3);
        // Cross-half sum via permlane32_swap: with src==dst==acc the two
        // results are (lower-half broadcast, upper-half broadcast); their sum
        // is acc[l&31] + acc[32+(l&31)] in every lane (order-insensitive).
        auto sw = __builtin_amdgcn_permlane32_swap(
            __float_as_uint(acc), __float_as_uint(acc), false, false);
        float full = __uint_as_float(sw[0]) + __uint_as_float(sw[1]);
        float hnew = tanhf(full + (isL1 ? bias1 : p));
        if (active && part == 0) {
            if (isL1) {
                hs1[wb][j] = hnew;
                out1[((long)b * TT + (i - 1)) * HH + j] = hnew;  // stays in flight
            } else {
                hs0[wb][j] = hnew;
            }
        }
        // LDS-visibility-only barrier: do NOT drain vmcnt (out1 stores /
        // pre0 prefetch remain outstanding across steps).
        asm volatile("s_waitcnt lgkmcnt(0)" ::: "memory");
        __builtin_amdgcn_s_barrier();
        asm volatile("" ::: "memory");
    }
    // Final hidden: h0^{T-1} in hs0[(TT-1)&1]=hs0[1], h1^{T-1} in hs1[TT&1]=hs1[0].
    if (tid < HH) {
        hout[b * HH + tid] = hs0[1][tid];
        hout[(BB + b) * HH + tid] = hs1[0][tid];
    }
}

// ---------------------------------------------------------------------------
// K3: logits = act @ fc_w^T + fc_b via f16 MFMA (16x16x32). (unchanged)
// Block tile 64(M) x 128(N), K=128 resident in LDS.
// ---------------------------------------------------------------------------
#define BM 64
#define BN 128
#define LDK 136

__global__ void __launch_bounds__(256) logits_kernel(
        const float* __restrict__ act,   // [8192,128]
        const float* __restrict__ fcw,   // [32000,128]
        const float* __restrict__ fcb,   // [32000]
        float* __restrict__ Cout) {      // [8192,32000]
    __shared__ __align__(16) _Float16 As[BM * LDK];
    __shared__ __align__(16) _Float16 Bs[BN * LDK];
    const int bn = blockIdx.x;
    const int bm = blockIdx.y;
    const int tid = threadIdx.x;

#pragma unroll
    for (int s = 0; s < 8; s++) {
        int f = tid + s * 256;
        int r = f >> 5, c4 = f & 31;
        float4 v = *(const float4*)(act + ((long)(bm * BM + r)) * HH + c4 * 4);
        _Float16* d = &As[r * LDK + c4 * 4];
        d[0] = (_Float16)v.x; d[1] = (_Float16)v.y;
        d[2] = (_Float16)v.z; d[3] = (_Float16)v.w;
    }
#pragma unroll
    for (int s = 0; s < 16; s++) {
        int f = tid + s * 256;
        int r = f >> 5, c4 = f & 31;
        float4 v = *(const float4*)(fcw + ((long)(bn * BN + r)) * HH + c4 * 4);
        _Float16* d = &Bs[r * LDK + c4 * 4];
        d[0] = (_Float16)v.x; d[1] = (_Float16)v.y;
        d[2] = (_Float16)v.z; d[3] = (_Float16)v.w;
    }
    __syncthreads();

    const int wv = tid >> 6;
    const int wm = wv >> 1, wn = wv & 1;
    const int r = tid & 15, q = (tid & 63) >> 4;

    floatx4 acc[2][4];
#pragma unroll
    for (int mt = 0; mt < 2; mt++)
#pragma unroll
        for (int nt = 0; nt < 4; nt++) acc[mt][nt] = (floatx4){0.f, 0.f, 0.f, 0.f};

#pragma unroll
    for (int kk = 0; kk < 4; kk++) {
        half8 af[2], bf[4];
#pragma unroll
        for (int mt = 0; mt < 2; mt++)
            af[mt] = *(const half8*)(&As[(wm * 32 + mt * 16 + r) * LDK + kk * 32 + q * 8]);
#pragma unroll
        for (int nt = 0; nt < 4; nt++)
            bf[nt] = *(const half8*)(&Bs[(wn * 64 + nt * 16 + r) * LDK + kk * 32 + q * 8]);
#pragma unroll
        for (int mt = 0; mt < 2; mt++)
#pragma unroll
            for (int nt = 0; nt < 4; nt++)
                acc[mt][nt] = __builtin_amdgcn_mfma_f32_16x16x32_f16(af[mt], bf[nt], acc[mt][nt], 0, 0, 0);
    }

#pragma unroll
    for (int mt = 0; mt < 2; mt++) {
#pragma unroll
        for (int nt = 0; nt < 4; nt++) {
            int gcol = bn * BN + wn * 64 + nt * 16 + r;
            float bias = fcb[gcol];
#pragma unroll
            for (int r4 = 0; r4 < 4; r4++) {
                int grow = bm * BM + wm * 32 + mt * 16 + q * 4 + r4;
                Cout[(long)grow * VV + gcol] = acc[mt][nt][r4] + bias;
            }
        }
    }
}

// ---------------------------------------------------------------------------
extern "C" void kernel_launch(void* const* d_in, const int* in_sizes, int n_in,
                              void* d_out, int out_size, void* d_ws, size_t ws_size,
                              hipStream_t stream) {
    const int*   x      = (const int*)d_in[0];
    const float* hidden = (const float*)d_in[1];
    const float* emb    = (const float*)d_in[2];
    const float* Wih0   = (const float*)d_in[3];
    const float* Whh0   = (const float*)d_in[4];
    const float* bih0   = (const float*)d_in[5];
    const float* bhh0   = (const float*)d_in[6];
    const float* Wih1   = (const float*)d_in[7];
    const float* Whh1   = (const float*)d_in[8];
    const float* bih1   = (const float*)d_in[9];
    const float* bhh1   = (const float*)d_in[10];
    const float* fcw    = (const float*)d_in[11];
    const float* fcb    = (const float*)d_in[12];

    float* logits = (float*)d_out;
    float* hout   = logits + (long)BB * TT * VV;   // new_hidden [2,B,H]

    float* wsA = (float*)d_ws;                     // [B,T,H] layer-0 pre-activations
    float* ws1 = wsA + (long)BB * TT * HH;         // [B,T,H] layer-1 outputs

    // Layer 0 pre-activations (embedding gather fused).
    preact_kernel<<<BB * TT, HH, 0, stream>>>(emb, x, Wih0, bih0, bhh0, wsA);
    // Fused 2-layer recurrence.
    rnn_fused_kernel<<<BB, 512, 0, stream>>>(wsA, Whh0, Wih1, Whh1, bih1, bhh1,
                                             hidden, ws1, hout);
    // Final projection to vocab.
    logits_kernel<<<dim3(VV / BN, (BB * TT) / BM), 256, 0, stream>>>(ws1, fcw, fcb, logits);
}